// Round 6
// baseline (213.395 us; speedup 1.0000x reference)
//
#include <hip/hip_runtime.h>

#define N_NODES 100000
#define DIM 64
#define N_EDGES 1250000
#define EPS 1e-12f

#define NREP 8                               // replicated histograms
#define SCAN_CHUNK 1024
#define NB ((N_NODES + SCAN_CHUNK - 1) / SCAN_CHUNK)   // 98 scan blocks

// ---- Pass 1: 8-way replicated histogram + per-replica rank.
// Replica r = e&7 spreads RMWs over 8x the cache lines to break per-line
// serialization at the memory-side atomic unit.
__global__ void hist_rank_kernel(const int* __restrict__ dst,
                                 int* __restrict__ deg8,
                                 int* __restrict__ rank) {
    int e = blockIdx.x * blockDim.x + threadIdx.x;
    if (e < N_EDGES) {
        int r = e & (NREP - 1);
        rank[e] = atomicAdd(&deg8[r * N_NODES + dst[e]], 1);
    }
}

// ---- Pass 1b: in-place exclusive prefix over the 8 replicas per node;
// also emits deg_total. All reads/writes coalesced (replica-major layout).
__global__ void replica_prefix_kernel(int* __restrict__ deg8,
                                      int* __restrict__ deg_total) {
    int i = blockIdx.x * blockDim.x + threadIdx.x;
    if (i < N_NODES) {
        int run = 0;
        #pragma unroll
        for (int r = 0; r < NREP; ++r) {
            int c = deg8[r * N_NODES + i];
            deg8[r * N_NODES + i] = run;   // becomes replica base offset
            run += c;
        }
        deg_total[i] = run;
    }
}

// ---- Pass 2a: per-block exclusive scan of deg_total ----
__global__ void scan_blocks_kernel(const int* __restrict__ deg,
                                   int* __restrict__ row_start,
                                   int* __restrict__ bsums) {
    __shared__ int lds[256];
    int t = threadIdx.x;
    int base = blockIdx.x * SCAN_CHUNK + t * 4;
    int v[4];
    int sum = 0;
    #pragma unroll
    for (int i = 0; i < 4; ++i) {
        int idx = base + i;
        v[i] = (idx < N_NODES) ? deg[idx] : 0;
        sum += v[i];
    }
    lds[t] = sum;
    __syncthreads();
    for (int off = 1; off < 256; off <<= 1) {
        int val = lds[t];
        int add = (t >= off) ? lds[t - off] : 0;
        __syncthreads();
        lds[t] = val + add;
        __syncthreads();
    }
    int excl = (t > 0) ? lds[t - 1] : 0;
    if (t == 255) bsums[blockIdx.x] = lds[255];
    int run = excl;
    #pragma unroll
    for (int i = 0; i < 4; ++i) {
        int idx = base + i;
        if (idx < N_NODES) row_start[idx] = run;
        run += v[i];
    }
}

// ---- Pass 2b: exclusive scan of block sums (single block) ----
__global__ void scan_bsums_kernel(int* __restrict__ bsums) {
    __shared__ int lds[128];
    int t = threadIdx.x;
    lds[t] = (t < NB) ? bsums[t] : 0;
    __syncthreads();
    for (int off = 1; off < 128; off <<= 1) {
        int val = lds[t];
        int add = (t >= off) ? lds[t - off] : 0;
        __syncthreads();
        lds[t] = val + add;
        __syncthreads();
    }
    int excl = (t > 0) ? lds[t - 1] : 0;
    if (t < NB) bsums[t] = excl;
}

// ---- Pass 3: scatter fill — no atomics.
// slot = row_start + block offset + replica base + within-replica rank.
__global__ void fill_adj_kernel(const int* __restrict__ src,
                                const int* __restrict__ dst,
                                const int* __restrict__ rank,
                                const int* __restrict__ row_start,
                                const int* __restrict__ bsums,
                                const int* __restrict__ deg8,
                                int* __restrict__ adj) {
    int e = blockIdx.x * blockDim.x + threadIdx.x;
    if (e < N_EDGES) {
        int d = dst[e];
        int r = e & (NREP - 1);
        int pos = row_start[d] + bsums[d >> 10] + deg8[r * N_NODES + d] + rank[e];
        adj[pos] = src[e];
    }
}

// ---- Pass 4: fused gather-mean + L2-normalize + relu(2h) ----
__global__ void aggregate_kernel(const float* __restrict__ x,
                                 const int* __restrict__ row_start,
                                 const int* __restrict__ bsums,
                                 const int* __restrict__ deg,
                                 const int* __restrict__ adj,
                                 float* __restrict__ out) {
    int node = blockIdx.x * (blockDim.x >> 6) + (threadIdx.x >> 6);
    if (node >= N_NODES) return;
    int lane = threadIdx.x & 63;
    int g    = lane >> 3;   // row slot 0..7
    int sub  = lane & 7;    // float4 index within half-row

    int start = row_start[node] + bsums[node >> 10];
    int degn  = deg[node];

    const float4* __restrict__ x4 = (const float4*)x;
    float a0x = 0.f, a0y = 0.f, a0z = 0.f, a0w = 0.f;
    float a1x = 0.f, a1y = 0.f, a1z = 0.f, a1w = 0.f;

    int e = g;
    for (; e + 8 < degn; e += 16) {
        int s0 = adj[start + e];
        int s1 = adj[start + e + 8];
        float4 v0 = x4[(size_t)s0 * 16 + sub];
        float4 v1 = x4[(size_t)s0 * 16 + 8 + sub];
        float4 v2 = x4[(size_t)s1 * 16 + sub];
        float4 v3 = x4[(size_t)s1 * 16 + 8 + sub];
        a0x += v0.x + v2.x; a0y += v0.y + v2.y;
        a0z += v0.z + v2.z; a0w += v0.w + v2.w;
        a1x += v1.x + v3.x; a1y += v1.y + v3.y;
        a1z += v1.z + v3.z; a1w += v1.w + v3.w;
    }
    if (e < degn) {
        int s0 = adj[start + e];
        float4 v0 = x4[(size_t)s0 * 16 + sub];
        float4 v1 = x4[(size_t)s0 * 16 + 8 + sub];
        a0x += v0.x; a0y += v0.y; a0z += v0.z; a0w += v0.w;
        a1x += v1.x; a1y += v1.y; a1z += v1.z; a1w += v1.w;
    }

    #pragma unroll
    for (int off = 8; off < 64; off <<= 1) {
        a0x += __shfl_xor(a0x, off, 64);
        a0y += __shfl_xor(a0y, off, 64);
        a0z += __shfl_xor(a0z, off, 64);
        a0w += __shfl_xor(a0w, off, 64);
        a1x += __shfl_xor(a1x, off, 64);
        a1y += __shfl_xor(a1y, off, 64);
        a1z += __shfl_xor(a1z, off, 64);
        a1w += __shfl_xor(a1w, off, 64);
    }

    float inv = 1.0f / fmaxf((float)degn, 1.0f);
    a0x *= inv; a0y *= inv; a0z *= inv; a0w *= inv;
    a1x *= inv; a1y *= inv; a1z *= inv; a1w *= inv;

    float ss = a0x*a0x + a0y*a0y + a0z*a0z + a0w*a0w
             + a1x*a1x + a1y*a1y + a1z*a1z + a1w*a1w;
    #pragma unroll
    for (int off = 1; off < 8; off <<= 1) ss += __shfl_xor(ss, off, 64);

    float scale = 2.0f / fmaxf(sqrtf(ss), EPS);
    if (g == 0) {
        float4 o0, o1;
        o0.x = fmaxf(a0x * scale, 0.0f); o0.y = fmaxf(a0y * scale, 0.0f);
        o0.z = fmaxf(a0z * scale, 0.0f); o0.w = fmaxf(a0w * scale, 0.0f);
        o1.x = fmaxf(a1x * scale, 0.0f); o1.y = fmaxf(a1y * scale, 0.0f);
        o1.z = fmaxf(a1z * scale, 0.0f); o1.w = fmaxf(a1w * scale, 0.0f);
        ((float4*)out)[(size_t)node * 16 + sub] = o0;
        ((float4*)out)[(size_t)node * 16 + 8 + sub] = o1;
    }
}

extern "C" void kernel_launch(void* const* d_in, const int* in_sizes, int n_in,
                              void* d_out, int out_size, void* d_ws, size_t ws_size,
                              hipStream_t stream) {
    const float* x  = (const float*)d_in[0];
    const int*   ei = (const int*)d_in[1];
    float* out = (float*)d_out;

    const int* src = ei;
    const int* dst = ei + N_EDGES;

    // ws: deg8[8N] | deg_total[N] | row_start[N] | bsums[128] | rank[E] | adj[E]
    int* deg8      = (int*)d_ws;
    int* deg_total = deg8 + NREP * N_NODES;
    int* row_start = deg_total + N_NODES;
    int* bsums     = row_start + N_NODES;
    int* rank      = bsums + 128;
    int* adj       = rank + N_EDGES;

    hipMemsetAsync(deg8, 0, (size_t)NREP * N_NODES * sizeof(int), stream);

    int eb = (N_EDGES + 255) / 256;
    hist_rank_kernel<<<eb, 256, 0, stream>>>(dst, deg8, rank);

    int nb2 = (N_NODES + 255) / 256;
    replica_prefix_kernel<<<nb2, 256, 0, stream>>>(deg8, deg_total);

    scan_blocks_kernel<<<NB, 256, 0, stream>>>(deg_total, row_start, bsums);
    scan_bsums_kernel<<<1, 128, 0, stream>>>(bsums);

    fill_adj_kernel<<<eb, 256, 0, stream>>>(src, dst, rank, row_start, bsums,
                                            deg8, adj);

    int waves_per_block = 256 / 64;
    int agg_blocks = (N_NODES + waves_per_block - 1) / waves_per_block;
    aggregate_kernel<<<agg_blocks, 256, 0, stream>>>(x, row_start, bsums,
                                                     deg_total, adj, out);
}

// Round 7
// 207.825 us; speedup vs baseline: 1.0268x; 1.0268x over previous
//
#include <hip/hip_runtime.h>

#define N_NODES 100000
#define DIM 64
#define N_EDGES 1250000
#define EPS 1e-12f

#define SCAN_CHUNK 1024
#define NB ((N_NODES + SCAN_CHUNK - 1) / SCAN_CHUNK)   // 98 scan blocks

typedef unsigned short ushort8 __attribute__((ext_vector_type(8)));

__device__ inline unsigned short f2bf(float f) {   // fp32 -> bf16 RNE
    unsigned int u = __float_as_uint(f);
    return (unsigned short)((u + 0x7FFFu + ((u >> 16) & 1u)) >> 16);
}
__device__ inline float bf2f(unsigned short h) {
    return __uint_as_float(((unsigned int)h) << 16);
}

// ---- Pass 0: x (fp32) -> xh (bf16). Threshold is 2.36e-2; bf16 gather
// error lands ~1e-3. Halves the dominant gather traffic.
__global__ void convert_kernel(const float4* __restrict__ x4,
                               ushort8* __restrict__ xh8) {
    int i = blockIdx.x * blockDim.x + threadIdx.x;
    if (i < N_NODES * DIM / 8) {
        float4 a = x4[2 * i];
        float4 b = x4[2 * i + 1];
        ushort8 o;
        o[0] = f2bf(a.x); o[1] = f2bf(a.y); o[2] = f2bf(a.z); o[3] = f2bf(a.w);
        o[4] = f2bf(b.x); o[5] = f2bf(b.y); o[6] = f2bf(b.z); o[7] = f2bf(b.w);
        xh8[i] = o;
    }
}

// ---- Pass 1: histogram + per-edge rank (plain — replication didn't pay) ----
__global__ void hist_rank_kernel(const int* __restrict__ dst,
                                 int* __restrict__ deg,
                                 int* __restrict__ rank) {
    int e = blockIdx.x * blockDim.x + threadIdx.x;
    if (e < N_EDGES) rank[e] = atomicAdd(&deg[dst[e]], 1);
}

// ---- Pass 2a: per-block exclusive scan of deg ----
__global__ void scan_blocks_kernel(const int* __restrict__ deg,
                                   int* __restrict__ row_start,
                                   int* __restrict__ bsums) {
    __shared__ int lds[256];
    int t = threadIdx.x;
    int base = blockIdx.x * SCAN_CHUNK + t * 4;
    int v[4];
    int sum = 0;
    #pragma unroll
    for (int i = 0; i < 4; ++i) {
        int idx = base + i;
        v[i] = (idx < N_NODES) ? deg[idx] : 0;
        sum += v[i];
    }
    lds[t] = sum;
    __syncthreads();
    for (int off = 1; off < 256; off <<= 1) {
        int val = lds[t];
        int add = (t >= off) ? lds[t - off] : 0;
        __syncthreads();
        lds[t] = val + add;
        __syncthreads();
    }
    int excl = (t > 0) ? lds[t - 1] : 0;
    if (t == 255) bsums[blockIdx.x] = lds[255];
    int run = excl;
    #pragma unroll
    for (int i = 0; i < 4; ++i) {
        int idx = base + i;
        if (idx < N_NODES) row_start[idx] = run;
        run += v[i];
    }
}

// ---- Pass 2b: exclusive scan of block sums; consumers add bsums[i>>10] ----
__global__ void scan_bsums_kernel(int* __restrict__ bsums) {
    __shared__ int lds[128];
    int t = threadIdx.x;
    lds[t] = (t < NB) ? bsums[t] : 0;
    __syncthreads();
    for (int off = 1; off < 128; off <<= 1) {
        int val = lds[t];
        int add = (t >= off) ? lds[t - off] : 0;
        __syncthreads();
        lds[t] = val + add;
        __syncthreads();
    }
    int excl = (t > 0) ? lds[t - 1] : 0;
    if (t < NB) bsums[t] = excl;
}

// ---- Pass 3: scatter fill — no atomics, fire-and-forget stores ----
__global__ void fill_adj_kernel(const int* __restrict__ src,
                                const int* __restrict__ dst,
                                const int* __restrict__ rank,
                                const int* __restrict__ row_start,
                                const int* __restrict__ bsums,
                                int* __restrict__ adj) {
    int e = blockIdx.x * blockDim.x + threadIdx.x;
    if (e < N_EDGES) {
        int d = dst[e];
        adj[row_start[d] + bsums[d >> 10] + rank[e]] = src[e];
    }
}

// ---- Pass 4: fused gather-mean (bf16 rows) + L2-normalize + relu(2h) ----
// One wave per node: 8 row-slots (g) x 8 chunks (sub); lane loads one 16B
// ushort8 chunk = cols 8*sub..8*sub+7; fp32 accumulation.
__global__ void aggregate_kernel(const ushort8* __restrict__ xh8,
                                 const int* __restrict__ row_start,
                                 const int* __restrict__ bsums,
                                 const int* __restrict__ deg,
                                 const int* __restrict__ adj,
                                 float* __restrict__ out) {
    int node = blockIdx.x * (blockDim.x >> 6) + (threadIdx.x >> 6);
    if (node >= N_NODES) return;
    int lane = threadIdx.x & 63;
    int g    = lane >> 3;   // row slot 0..7
    int sub  = lane & 7;    // ushort8 chunk within row

    int start = row_start[node] + bsums[node >> 10];
    int degn  = deg[node];

    float acc[8] = {0.f, 0.f, 0.f, 0.f, 0.f, 0.f, 0.f, 0.f};

    int e = g;
    for (; e + 8 < degn; e += 16) {
        int s0 = adj[start + e];
        int s1 = adj[start + e + 8];
        ushort8 v0 = xh8[(size_t)s0 * 8 + sub];
        ushort8 v1 = xh8[(size_t)s1 * 8 + sub];
        #pragma unroll
        for (int k = 0; k < 8; ++k) acc[k] += bf2f(v0[k]) + bf2f(v1[k]);
    }
    if (e < degn) {
        int s0 = adj[start + e];
        ushort8 v0 = xh8[(size_t)s0 * 8 + sub];
        #pragma unroll
        for (int k = 0; k < 8; ++k) acc[k] += bf2f(v0[k]);
    }

    // reduce across the 8 row-slots (lane bits 3,4,5)
    #pragma unroll
    for (int off = 8; off < 64; off <<= 1) {
        #pragma unroll
        for (int k = 0; k < 8; ++k) acc[k] += __shfl_xor(acc[k], off, 64);
    }

    float inv = 1.0f / fmaxf((float)degn, 1.0f);
    #pragma unroll
    for (int k = 0; k < 8; ++k) acc[k] *= inv;

    float ss = 0.f;
    #pragma unroll
    for (int k = 0; k < 8; ++k) ss += acc[k] * acc[k];
    #pragma unroll
    for (int off = 1; off < 8; off <<= 1) ss += __shfl_xor(ss, off, 64);

    float scale = 2.0f / fmaxf(sqrtf(ss), EPS);
    if (g == 0) {
        float4 o0, o1;
        o0.x = fmaxf(acc[0] * scale, 0.0f); o0.y = fmaxf(acc[1] * scale, 0.0f);
        o0.z = fmaxf(acc[2] * scale, 0.0f); o0.w = fmaxf(acc[3] * scale, 0.0f);
        o1.x = fmaxf(acc[4] * scale, 0.0f); o1.y = fmaxf(acc[5] * scale, 0.0f);
        o1.z = fmaxf(acc[6] * scale, 0.0f); o1.w = fmaxf(acc[7] * scale, 0.0f);
        ((float4*)out)[(size_t)node * 16 + 2 * sub]     = o0;
        ((float4*)out)[(size_t)node * 16 + 2 * sub + 1] = o1;
    }
}

extern "C" void kernel_launch(void* const* d_in, const int* in_sizes, int n_in,
                              void* d_out, int out_size, void* d_ws, size_t ws_size,
                              hipStream_t stream) {
    const float* x  = (const float*)d_in[0];
    const int*   ei = (const int*)d_in[1];
    float* out = (float*)d_out;

    const int* src = ei;
    const int* dst = ei + N_EDGES;

    // ws: xh[N*DIM bf16, 16B-aligned first] | deg[N] | row_start[N] |
    //     bsums[128] | rank[E] | adj[E]    (~23.6 MB total)
    ushort8* xh    = (ushort8*)d_ws;
    int* deg       = (int*)((char*)d_ws + (size_t)N_NODES * DIM * 2);
    int* row_start = deg + N_NODES;
    int* bsums     = row_start + N_NODES;
    int* rank      = bsums + 128;
    int* adj       = rank + N_EDGES;

    hipMemsetAsync(deg, 0, N_NODES * sizeof(int), stream);

    int cvb = (N_NODES * DIM / 8 + 255) / 256;
    convert_kernel<<<cvb, 256, 0, stream>>>((const float4*)x, xh);

    int eb = (N_EDGES + 255) / 256;
    hist_rank_kernel<<<eb, 256, 0, stream>>>(dst, deg, rank);

    scan_blocks_kernel<<<NB, 256, 0, stream>>>(deg, row_start, bsums);
    scan_bsums_kernel<<<1, 128, 0, stream>>>(bsums);

    fill_adj_kernel<<<eb, 256, 0, stream>>>(src, dst, rank, row_start, bsums, adj);

    int waves_per_block = 256 / 64;
    int agg_blocks = (N_NODES + waves_per_block - 1) / waves_per_block;
    aggregate_kernel<<<agg_blocks, 256, 0, stream>>>(xh, row_start, bsums, deg,
                                                     adj, out);
}